// Round 10
// baseline (728.268 us; speedup 1.0000x reference)
//
#include <hip/hip_runtime.h>
#include <stdint.h>

#define B_    8
#define DK_   128
#define DV_   512
#define M_    3136      // H*W
#define N_    6272      // T*H*W
#define NT32_ 196       // N_/32 tiles of 32 n
#define MG32_ 98        // M_/32 static m-groups of 32
#define NSEG_ 8
#define TH_   30.0f
#define MARGIN_ 36.0f
#define CAP_  8         // slots per (column, segment, lane-half) owner

typedef short bf16x8 __attribute__((ext_vector_type(8)));
typedef float f32x16 __attribute__((ext_vector_type(16)));
typedef unsigned short u16x8 __attribute__((ext_vector_type(8)));

__device__ __forceinline__ unsigned short f2bf(float x) {
  unsigned u = __float_as_uint(x);
  return (unsigned short)((u + 0x7fffu + ((u >> 16) & 1u)) >> 16);
}
__device__ __forceinline__ float bf2f(unsigned short h) {
  return __uint_as_float(((unsigned)h) << 16);
}

// ---- fused prep: vectorized transposes + q-scan ----
// grid: [0,784) qkeyT+qkb; [784,2352) mkeyT + mkt(tiled, mask-zeroed);
//       [2352,8624) mvalT; [8624,8632) q scan
__global__ __launch_bounds__(256)
void prep_kernel(const float* __restrict__ qkey, const int* __restrict__ qmask,
                 const float* __restrict__ mkey, const float* __restrict__ mval,
                 const int* __restrict__ mmask,
                 float* __restrict__ qkeyT, unsigned short* __restrict__ qkb,
                 float* __restrict__ mkeyT, unsigned short* __restrict__ mkt,
                 unsigned short* __restrict__ mvalT,
                 int* __restrict__ qlist, int* __restrict__ qcnt) {
  __shared__ float T[64][65];
  int r = blockIdx.x;
  int tid = threadIdx.x;
  int r16 = tid >> 4, c4 = (tid & 15) << 2;
  if (r < 784) {                       // qkey [B][128][M] -> fp32+bf16 [B][M][128], x40
    int xt = r % 49, dt = (r / 49) & 1, b = r / 98;
    const float* src = qkey + ((size_t)b * DK_ + dt * 64) * M_ + xt * 64;
    #pragma unroll
    for (int i = 0; i < 4; ++i) {
      int row = i * 16 + r16;
      float4 v = *(const float4*)&src[(size_t)row * M_ + c4];
      T[row][c4] = v.x; T[row][c4 + 1] = v.y; T[row][c4 + 2] = v.z; T[row][c4 + 3] = v.w;
    }
    __syncthreads();
    #pragma unroll
    for (int i = 0; i < 4; ++i) {
      int xl = i * 16 + r16;
      float4 v = make_float4(40.f * T[c4][xl], 40.f * T[c4 + 1][xl],
                             40.f * T[c4 + 2][xl], 40.f * T[c4 + 3][xl]);
      size_t idx = ((size_t)b * M_ + xt * 64 + xl) * DK_ + dt * 64 + c4;
      *(float4*)&qkeyT[idx] = v;
      ushort4 h;
      h.x = f2bf(v.x); h.y = f2bf(v.y); h.z = f2bf(v.z); h.w = f2bf(v.w);
      *(ushort4*)&qkb[idx] = h;
    }
  } else if (r < 2352) {               // mkey -> fp32 T (exact) + bf16 MFMA-tiled (mask-zeroed)
    int r2 = r - 784;
    int xt = r2 % 98, dt = (r2 / 98) & 1, b = r2 / 196;
    const float* src = mkey + ((size_t)b * DK_ + dt * 64) * N_ + xt * 64;
    #pragma unroll
    for (int i = 0; i < 4; ++i) {
      int row = i * 16 + r16;
      float4 v = *(const float4*)&src[(size_t)row * N_ + c4];
      T[row][c4] = v.x; T[row][c4 + 1] = v.y; T[row][c4 + 2] = v.z; T[row][c4 + 3] = v.w;
    }
    __syncthreads();
    #pragma unroll
    for (int i = 0; i < 4; ++i) {
      int xl = i * 16 + r16;
      int n = xt * 64 + xl;
      bool act = (mmask[b * N_ + n] != 0);
      float4 v = make_float4(T[c4][xl], T[c4 + 1][xl], T[c4 + 2][xl], T[c4 + 3][xl]);
      size_t idx = ((size_t)b * N_ + n) * DK_ + dt * 64 + c4;
      *(float4*)&mkeyT[idx] = v;
      ushort4 h;
      if (act) { h.x = f2bf(v.x); h.y = f2bf(v.y); h.z = f2bf(v.z); h.w = f2bf(v.w); }
      else     { h.x = 0; h.y = 0; h.z = 0; h.w = 0; }
      // tiled layout: [tile32][kc8][lane64][8bf16]; lane = ((k>>3)&1)*32 + (n&31)
      int k = dt * 64 + c4;
      int tile = n >> 5;
      int kc = k >> 4;
      int ln = (((k >> 3) & 1) << 5) | (n & 31);
      size_t ta = (size_t)b * (NT32_ * 4096) +
                  (((size_t)(tile * 8 + kc) * 64 + ln) << 3) + (k & 7);
      *(ushort4*)&mkt[ta] = h;
    }
  } else if (r < 8624) {               // mval -> bf16 [B][N][512]
    int r3 = r - 2352;
    int nt = r3 % 98, dvt = (r3 / 98) & 7, b = r3 / 784;
    const float* src = mval + ((size_t)b * DV_ + dvt * 64) * N_ + nt * 64;
    #pragma unroll
    for (int i = 0; i < 4; ++i) {
      int row = i * 16 + r16;
      float4 v = *(const float4*)&src[(size_t)row * N_ + c4];
      T[row][c4] = v.x; T[row][c4 + 1] = v.y; T[row][c4 + 2] = v.z; T[row][c4 + 3] = v.w;
    }
    __syncthreads();
    #pragma unroll
    for (int i = 0; i < 4; ++i) {
      int xl = i * 16 + r16;
      ushort4 h;
      h.x = f2bf(T[c4][xl]); h.y = f2bf(T[c4 + 1][xl]);
      h.z = f2bf(T[c4 + 2][xl]); h.w = f2bf(T[c4 + 3][xl]);
      *(ushort4*)&mvalT[((size_t)b * N_ + nt * 64 + xl) * DV_ + dvt * 64 + c4] = h;
    }
  } else {                             // q-mask compaction
    int b = r - 8624;
    __shared__ int wsum[4];
    __shared__ int cbase;
    int lane = tid & 63, wv = tid >> 6;
    if (tid == 0) cbase = 0;
    __syncthreads();
    for (int base = 0; base < M_; base += 256) {
      int i = base + tid;
      int flag = (i < M_) ? (qmask[b * M_ + i] != 0) : 0;
      unsigned long long bal = __ballot(flag);
      int prefix = __popcll(bal & ((1ull << lane) - 1ull));
      if (lane == 0) wsum[wv] = __popcll(bal);
      __syncthreads();
      int woff = 0;
      for (int t = 0; t < wv; ++t) woff += wsum[t];
      int total = wsum[0] + wsum[1] + wsum[2] + wsum[3];
      if (flag) qlist[b * M_ + cbase + woff + prefix] = i;
      __syncthreads();
      if (tid == 0) cbase += total;
      __syncthreads();
    }
    if (tid == 0) qcnt[b] = cbase;
  }
}

// ---- bf16-MFMA score: atomic-free; per-owner private buckets + reg slot ctr ----
// one wave = one (batch, 32-m-group, n-segment); owner = (column, seg, lane-half)
__global__ __launch_bounds__(256)
void score_mfma(const unsigned short* __restrict__ qkb,
                const unsigned short* __restrict__ mkt,
                const int* __restrict__ qlist, const int* __restrict__ qcnt,
                unsigned char* __restrict__ bcnt8, unsigned* __restrict__ bucket) {
  int lane = threadIdx.x & 63;
  int gid = (blockIdx.x << 2) + (threadIdx.x >> 6);   // global wave id, 0..6271
  int seg = gid & (NSEG_ - 1);
  int t   = gid >> 3;            // 0..783
  int mg  = t % MG32_;
  int b   = t / MG32_;
  int mc = qcnt[b];
  if (mg * 32 >= mc) return;
  int t0 = (NT32_ * seg) / NSEG_;
  int t1 = (NT32_ * (seg + 1)) / NSEG_;
  int l31 = lane & 31, lhi = lane >> 5;

  // Q fragments (x40 prefolded bf16); lane's m column = mg*32 + l31
  int cm = mg * 32 + l31;
  int col = (cm < mc) ? qlist[b * M_ + cm] : qlist[b * M_];
  int mo  = (cm < mc) ? col : -1;
  const unsigned short* qrow = qkb + ((size_t)b * M_ + col) * DK_;
  bf16x8 qf[8];
  #pragma unroll
  for (int kc = 0; kc < 8; ++kc)
    qf[kc] = *(const bf16x8*)(qrow + (kc * 2 + lhi) * 8);

  const unsigned short* A_b = mkt + (size_t)b * (NT32_ * 4096) + lane * 8;
  float runmax = -3.0e38f;
  unsigned slot = 0;                      // private slot counter (register)
  size_t bbase = ((size_t)(b * M_ + (mo >= 0 ? mo : 0)) << 7) + ((seg * 2 + lhi) << 3);

  auto loadA = [&](bf16x8* dst, int tt) {
    const unsigned short* p = A_b + (size_t)tt * 4096;
    #pragma unroll
    for (int kc = 0; kc < 8; ++kc) dst[kc] = *(const bf16x8*)(p + kc * 512);
  };
  auto comp2 = [&](const bf16x8* Aa, const bf16x8* Ab, f32x16& xa, f32x16& xb) {
    #pragma unroll
    for (int r = 0; r < 16; ++r) { xa[r] = 0.f; xb[r] = 0.f; }
    #pragma unroll
    for (int kc = 0; kc < 8; ++kc) {     // two independent 8-deep chains, interleaved
      xa = __builtin_amdgcn_mfma_f32_32x32x16_bf16(Aa[kc], qf[kc], xa, 0, 0, 0);
      xb = __builtin_amdgcn_mfma_f32_32x32x16_bf16(Ab[kc], qf[kc], xb, 0, 0, 0);
    }
  };
  auto comp1 = [&](const bf16x8* Aa, f32x16& xa) {
    #pragma unroll
    for (int r = 0; r < 16; ++r) xa[r] = 0.f;
    #pragma unroll
    for (int kc = 0; kc < 8; ++kc)
      xa = __builtin_amdgcn_mfma_f32_32x32x16_bf16(Aa[kc], qf[kc], xa, 0, 0, 0);
  };
  auto epi = [&](const f32x16& acc, int tt) {
    float cmxl = acc[0];
    #pragma unroll
    for (int r = 1; r < 16; ++r) cmxl = fmaxf(cmxl, acc[r]);
    float cmx = fmaxf(cmxl, __shfl_xor(cmxl, 32));
    runmax = fmaxf(runmax, cmx);          // masked rows score exactly 0, never dominate
    if (mo >= 0 && cmxl >= runmax - MARGIN_) {   // skip-guard
      float thr = runmax - MARGIN_;
      #pragma unroll
      for (int r = 0; r < 16; ++r) {
        const int pos = (r & 3) + ((r >> 2) << 3);
        if (acc[r] >= thr) {              // fire-and-forget store, reg slot ctr
          if (slot < (unsigned)CAP_)
            bucket[bbase + slot] = (unsigned)(tt * 32 + pos + (lhi << 2));
          ++slot;
        }
      }
    }
  };

  bf16x8 A0[8], A1[8];
  int tt = t0;
  loadA(A0, tt);
  if (tt + 1 < t1) loadA(A1, tt + 1);
  while (tt + 1 < t1) {
    f32x16 xa, xb;
    comp2(A0, A1, xa, xb);
    int nx = tt + 2;
    if (nx < t1) {                     // prefetch next pair before epilogue VALU
      loadA(A0, nx);
      if (nx + 1 < t1) loadA(A1, nx + 1);
    }
    epi(xa, tt);
    epi(xb, tt + 1);
    tt = nx;
  }
  if (tt < t1) {                       // odd tail tile
    f32x16 xa;
    comp1(A0, xa);
    epi(xa, tt);
  }
  if (mo >= 0)                         // final count, plain byte store (unique owner)
    bcnt8[((size_t)(b * M_ + mo) << 4) + (seg * 2 + lhi)] =
        (unsigned char)(slot > 255u ? 255u : slot);
}

__device__ __forceinline__ float dot128(const float* __restrict__ q,
                                        const float* __restrict__ k) {
  float s = 0.f;
  #pragma unroll 8
  for (int i = 0; i < DK_; i += 4) {
    float4 a = *(const float4*)&q[i];
    float4 bb = *(const float4*)&k[i];
    s += a.x * bb.x + a.y * bb.y + a.z * bb.z + a.w * bb.w;
  }
  return s;
}

// ---- PV: one wave per active column; gather 16 mini-buckets, exact rescore ----
__global__ __launch_bounds__(256)
void pv_exact(const float* __restrict__ qkeyT, const float* __restrict__ mkeyT,
              const unsigned short* __restrict__ mvalT,
              const int* __restrict__ qlist, const int* __restrict__ qcnt,
              const int* __restrict__ mmask,
              const unsigned char* __restrict__ bcnt8, const unsigned* __restrict__ bucket,
              unsigned short* __restrict__ outT) {
  int b = blockIdx.y;
  int wv = threadIdx.x >> 6, lane = threadIdx.x & 63;
  int c = blockIdx.x * 4 + wv;
  if (c >= qcnt[b]) return;
  int m = qlist[b * M_ + c];
  const float* qrow = qkeyT + ((size_t)b * M_ + m) * DK_;
  float acc[8] = {0.f, 0.f, 0.f, 0.f, 0.f, 0.f, 0.f, 0.f};
  float lsum = 0.f;

  // 16 sub-counts for this column (u8 x16 = one 16B load)
  uint4 cw = *(const uint4*)(bcnt8 + ((size_t)(b * M_ + m) << 4));
  unsigned cn[16];
  #pragma unroll
  for (int i = 0; i < 16; ++i) {
    unsigned wrd = (i < 4) ? cw.x : (i < 8) ? cw.y : (i < 12) ? cw.z : cw.w;
    cn[i] = (wrd >> ((i & 3) * 8)) & 0xffu;
  }
  bool ovf = false;
  unsigned total = 0;
  #pragma unroll
  for (int i = 0; i < 16; ++i) { ovf |= (cn[i] > (unsigned)CAP_); total += cn[i]; }

  if (!ovf) {
    size_t colb = ((size_t)(b * M_ + m) << 7);
    auto gather = [&](unsigned idx) -> int {
      int n = -1;
      unsigned off = idx;
      #pragma unroll
      for (int s = 0; s < 16; ++s) {
        unsigned cc = cn[s];
        if (n < 0) {
          if (off < cc) n = (int)bucket[colb + s * 8 + off];
          else off -= cc;
        }
      }
      return n;
    };
    int n0 = (lane < (int)total) ? gather(lane) : -1;
    int n1 = (lane + 64 < (int)total) ? gather(lane + 64) : -1;
    if (n0 >= 0 && mmask[b * N_ + n0] == 0) n0 = -1;   // drop masked strays
    if (n1 >= 0 && mmask[b * N_ + n1] == 0) n1 = -1;
    float s0 = (n0 >= 0) ? dot128(qrow, mkeyT + ((size_t)b * N_ + n0) * DK_) : -3.0e38f;
    float s1 = (n1 >= 0) ? dot128(qrow, mkeyT + ((size_t)b * N_ + n1) * DK_) : -3.0e38f;
    float mx = fmaxf(s0, s1);
    #pragma unroll
    for (int o = 32; o > 0; o >>= 1) mx = fmaxf(mx, __shfl_xor(mx, o));
    float e0 = (n0 >= 0 && s0 >= mx - TH_) ? expf(s0 - mx) : 0.f;
    float e1 = (n1 >= 0 && s1 >= mx - TH_) ? expf(s1 - mx) : 0.f;
    lsum = e0 + e1;
    #pragma unroll
    for (int o = 32; o > 0; o >>= 1) lsum += __shfl_xor(lsum, o);
    unsigned long long alive = __ballot(e0 > 0.f);
    while (alive) {
      int lb = __ffsll((unsigned long long)alive) - 1;
      alive &= alive - 1;
      float w = __shfl(e0, lb);
      int nn = __shfl(n0, lb);
      u16x8 vvv = *(const u16x8*)(mvalT + ((size_t)b * N_ + nn) * DV_ + lane * 8);
      #pragma unroll
      for (int r = 0; r < 8; ++r) acc[r] += w * bf2f(vvv[r]);
    }
    alive = __ballot(e1 > 0.f);
    while (alive) {
      int lb = __ffsll((unsigned long long)alive) - 1;
      alive &= alive - 1;
      float w = __shfl(e1, lb);
      int nn = __shfl(n1, lb);
      u16x8 vvv = *(const u16x8*)(mvalT + ((size_t)b * N_ + nn) * DV_ + lane * 8);
      #pragma unroll
      for (int r = 0; r < 8; ++r) acc[r] += w * bf2f(vvv[r]);
    }
  } else {
    // overflow fallback (rare): exact dense two-pass over all active n
    float mx = -3.0e38f;
    for (int base = 0; base < N_; base += 64) {
      int n = base + lane;
      float sv = -3.0e38f;
      if (mmask[b * N_ + n] != 0)
        sv = dot128(qrow, mkeyT + ((size_t)b * N_ + n) * DK_);
      mx = fmaxf(mx, sv);
    }
    #pragma unroll
    for (int o = 32; o > 0; o >>= 1) mx = fmaxf(mx, __shfl_xor(mx, o));
    for (int base = 0; base < N_; base += 64) {
      int n = base + lane;
      bool act = (mmask[b * N_ + n] != 0);
      float sv = -3.0e38f;
      if (act) sv = dot128(qrow, mkeyT + ((size_t)b * N_ + n) * DK_);
      float e = (act && sv >= mx - TH_) ? expf(sv - mx) : 0.f;
      lsum += e;
      unsigned long long alive = __ballot(e > 0.f);
      while (alive) {
        int lb = __ffsll((unsigned long long)alive) - 1;
        alive &= alive - 1;
        float w = __shfl(e, lb);
        int nn = __shfl(n, lb);
        u16x8 vvv = *(const u16x8*)(mvalT + ((size_t)b * N_ + nn) * DV_ + lane * 8);
        #pragma unroll
        for (int r = 0; r < 8; ++r) acc[r] += w * bf2f(vvv[r]);
      }
    }
    #pragma unroll
    for (int o = 32; o > 0; o >>= 1) lsum += __shfl_xor(lsum, o);
  }

  float inv = (lsum > 0.f) ? 1.0f / lsum : 0.0f;
  u16x8 ov;
  #pragma unroll
  for (int r = 0; r < 8; ++r) ov[r] = f2bf(acc[r] * inv);
  *(u16x8*)(outT + ((size_t)b * M_ + m) * DV_ + lane * 8) = ov;
}

// ---- transpose outT bf16 [B][M][Dv] -> out fp32 [B][Dv][M], applying qmask ----
__global__ __launch_bounds__(256)
void finalize_T(const unsigned short* __restrict__ outT, const int* __restrict__ qmask,
                float* __restrict__ out) {
  __shared__ float T[64][65];
  int b = blockIdx.z, dvt = blockIdx.y, mt = blockIdx.x;
  int lane = threadIdx.x & 63, ri = threadIdx.x >> 6;
  #pragma unroll
  for (int k = 0; k < 16; ++k) {
    int ml = ri * 16 + k;
    int m = mt * 64 + ml;
    bool act = (qmask[b * M_ + m] != 0);
    T[ml][lane] = act ? bf2f(outT[((size_t)b * M_ + m) * DV_ + dvt * 64 + lane]) : 0.f;
  }
  __syncthreads();
  #pragma unroll
  for (int k = 0; k < 16; ++k) {
    int dvl = ri * 16 + k;
    out[((size_t)b * DV_ + dvt * 64 + dvl) * M_ + mt * 64 + lane] = T[lane][dvl];
  }
}

extern "C" void kernel_launch(void* const* d_in, const int* in_sizes, int n_in,
                              void* d_out, int out_size, void* d_ws, size_t ws_size,
                              hipStream_t stream) {
  const float* qkey  = (const float*)d_in[0];
  const int*   qmask = (const int*)d_in[1];
  const float* mkey  = (const float*)d_in[2];
  const float* mval  = (const float*)d_in[3];
  const int*   mmask = (const int*)d_in[4];
  float* out = (float*)d_out;

  uint8_t* w = (uint8_t*)d_ws;
  unsigned char*  bcnt8  = (unsigned char*)(w + 0);         // B*M*16 u8 -> 401408
  int*            qcnt   = (int*)(w + 401408);
  int*            qlist  = (int*)(w + 401536);              // B*M -> 501888
  unsigned*       bucket = (unsigned*)(w + 501888);         // B*M*16*8 u32 -> 13346944
  float*          qkeyT  = (float*)(w + 13346944);          // B*M*128 f32 (x40)
  float*          mkeyT  = (float*)(w + 26192000);          // B*N*128 f32 (exact)
  unsigned short* qkb    = (unsigned short*)(w + 51882112); // B*M*128 bf16 (x40)
  unsigned short* mkt    = (unsigned short*)(w + 58304640); // B*196*8KB bf16 tiled
  unsigned short* outTb  = (unsigned short*)(w + 71149696); // B*M*512 bf16
  unsigned short* mvalT  = (unsigned short*)(w + 96839808); // B*N*512 bf16
  // end: 148,220,032 bytes == workspace size proven available in round 3

  prep_kernel<<<8632, 256, 0, stream>>>(qkey, qmask, mkey, mval, mmask,
                                        qkeyT, qkb, mkeyT, mkt, mvalT,
                                        qlist, qcnt);

  // 6272 static waves (8b x 98mg x 8seg) = 1568 blocks of 4 independent waves
  score_mfma<<<B_ * MG32_ * NSEG_ / 4, 256, 0, stream>>>(
      qkb, mkt, qlist, qcnt, bcnt8, bucket);

  pv_exact<<<dim3(M_ / 4, B_), 256, 0, stream>>>(
      qkeyT, mkeyT, mvalT, qlist, qcnt, mmask, bcnt8, bucket, outTb);

  finalize_T<<<dim3(M_ / 64, DV_ / 64, B_), 256, 0, stream>>>(outTb, qmask, out);
}

// Round 11
// 532.623 us; speedup vs baseline: 1.3673x; 1.3673x over previous
//
#include <hip/hip_runtime.h>
#include <stdint.h>

#define B_    8
#define DK_   128
#define DV_   512
#define M_    3136      // H*W
#define N_    6272      // T*H*W
#define NT32_ 196       // N_/32 tiles of 32 n
#define MG32_ 98        // M_/32 static m-groups of 32
#define NSEG_ 8
#define TH_   30.0f
#define MARGIN_ 36.0f
#define CAP_  12        // slots per (column, segment, lane-half) owner stream
#define STRD_ (16 * CAP_)   // u32 per column

typedef short bf16x8 __attribute__((ext_vector_type(8)));
typedef float f32x16 __attribute__((ext_vector_type(16)));
typedef unsigned short u16x8 __attribute__((ext_vector_type(8)));

__device__ __forceinline__ unsigned short f2bf(float x) {
  unsigned u = __float_as_uint(x);
  return (unsigned short)((u + 0x7fffu + ((u >> 16) & 1u)) >> 16);
}
__device__ __forceinline__ float bf2f(unsigned short h) {
  return __uint_as_float(((unsigned)h) << 16);
}

// ---- fused prep: vectorized transposes + q-scan ----
// grid: [0,784) qkeyT; [784,2352) mkeyT + mkt(tiled, mask-zeroed);
//       [2352,8624) mvalT; [8624,8632) q scan
__global__ __launch_bounds__(256)
void prep_kernel(const float* __restrict__ qkey, const int* __restrict__ qmask,
                 const float* __restrict__ mkey, const float* __restrict__ mval,
                 const int* __restrict__ mmask,
                 float* __restrict__ qkeyT,
                 float* __restrict__ mkeyT, unsigned short* __restrict__ mkt,
                 unsigned short* __restrict__ mvalT,
                 int* __restrict__ qlist, int* __restrict__ qcnt) {
  __shared__ float T[64][65];
  int r = blockIdx.x;
  int tid = threadIdx.x;
  int r16 = tid >> 4, c4 = (tid & 15) << 2;
  if (r < 784) {                       // qkey [B][128][M] -> fp32 [B][M][128], x40
    int xt = r % 49, dt = (r / 49) & 1, b = r / 98;
    const float* src = qkey + ((size_t)b * DK_ + dt * 64) * M_ + xt * 64;
    #pragma unroll
    for (int i = 0; i < 4; ++i) {
      int row = i * 16 + r16;
      float4 v = *(const float4*)&src[(size_t)row * M_ + c4];
      T[row][c4] = v.x; T[row][c4 + 1] = v.y; T[row][c4 + 2] = v.z; T[row][c4 + 3] = v.w;
    }
    __syncthreads();
    #pragma unroll
    for (int i = 0; i < 4; ++i) {
      int xl = i * 16 + r16;
      float4 v = make_float4(40.f * T[c4][xl], 40.f * T[c4 + 1][xl],
                             40.f * T[c4 + 2][xl], 40.f * T[c4 + 3][xl]);
      *(float4*)&qkeyT[((size_t)b * M_ + xt * 64 + xl) * DK_ + dt * 64 + c4] = v;
    }
  } else if (r < 2352) {               // mkey -> fp32 T (exact) + bf16 MFMA-tiled (mask-zeroed)
    int r2 = r - 784;
    int xt = r2 % 98, dt = (r2 / 98) & 1, b = r2 / 196;
    const float* src = mkey + ((size_t)b * DK_ + dt * 64) * N_ + xt * 64;
    #pragma unroll
    for (int i = 0; i < 4; ++i) {
      int row = i * 16 + r16;
      float4 v = *(const float4*)&src[(size_t)row * N_ + c4];
      T[row][c4] = v.x; T[row][c4 + 1] = v.y; T[row][c4 + 2] = v.z; T[row][c4 + 3] = v.w;
    }
    __syncthreads();
    #pragma unroll
    for (int i = 0; i < 4; ++i) {
      int xl = i * 16 + r16;
      int n = xt * 64 + xl;
      bool act = (mmask[b * N_ + n] != 0);
      float4 v = make_float4(T[c4][xl], T[c4 + 1][xl], T[c4 + 2][xl], T[c4 + 3][xl]);
      size_t idx = ((size_t)b * N_ + n) * DK_ + dt * 64 + c4;
      *(float4*)&mkeyT[idx] = v;
      ushort4 h;
      if (act) { h.x = f2bf(v.x); h.y = f2bf(v.y); h.z = f2bf(v.z); h.w = f2bf(v.w); }
      else     { h.x = 0; h.y = 0; h.z = 0; h.w = 0; }
      // tiled layout: [tile32][kc8][lane64][8bf16]; lane = ((k>>3)&1)*32 + (n&31)
      int k = dt * 64 + c4;
      int tile = n >> 5;
      int kc = k >> 4;
      int ln = (((k >> 3) & 1) << 5) | (n & 31);
      size_t ta = (size_t)b * (NT32_ * 4096) +
                  (((size_t)(tile * 8 + kc) * 64 + ln) << 3) + (k & 7);
      *(ushort4*)&mkt[ta] = h;
    }
  } else if (r < 8624) {               // mval -> bf16 [B][N][512]
    int r3 = r - 2352;
    int nt = r3 % 98, dvt = (r3 / 98) & 7, b = r3 / 784;
    const float* src = mval + ((size_t)b * DV_ + dvt * 64) * N_ + nt * 64;
    #pragma unroll
    for (int i = 0; i < 4; ++i) {
      int row = i * 16 + r16;
      float4 v = *(const float4*)&src[(size_t)row * N_ + c4];
      T[row][c4] = v.x; T[row][c4 + 1] = v.y; T[row][c4 + 2] = v.z; T[row][c4 + 3] = v.w;
    }
    __syncthreads();
    #pragma unroll
    for (int i = 0; i < 4; ++i) {
      int xl = i * 16 + r16;
      ushort4 h;
      h.x = f2bf(T[c4][xl]); h.y = f2bf(T[c4 + 1][xl]);
      h.z = f2bf(T[c4 + 2][xl]); h.w = f2bf(T[c4 + 3][xl]);
      *(ushort4*)&mvalT[((size_t)b * N_ + nt * 64 + xl) * DV_ + dvt * 64 + c4] = h;
    }
  } else {                             // q-mask compaction
    int b = r - 8624;
    __shared__ int wsum[4];
    __shared__ int cbase;
    int lane = tid & 63, wv = tid >> 6;
    if (tid == 0) cbase = 0;
    __syncthreads();
    for (int base = 0; base < M_; base += 256) {
      int i = base + tid;
      int flag = (i < M_) ? (qmask[b * M_ + i] != 0) : 0;
      unsigned long long bal = __ballot(flag);
      int prefix = __popcll(bal & ((1ull << lane) - 1ull));
      if (lane == 0) wsum[wv] = __popcll(bal);
      __syncthreads();
      int woff = 0;
      for (int t = 0; t < wv; ++t) woff += wsum[t];
      int total = wsum[0] + wsum[1] + wsum[2] + wsum[3];
      if (flag) qlist[b * M_ + cbase + woff + prefix] = i;
      __syncthreads();
      if (tid == 0) cbase += total;
      __syncthreads();
    }
    if (tid == 0) qcnt[b] = cbase;
  }
}

// ---- bf16-MFMA score: atomic-free; per-owner private buckets + reg slot ctr ----
// one wave = one (batch, 32-m-group, n-segment); owner = (column, seg, lane-half)
__global__ __launch_bounds__(256)
void score_mfma(const float* __restrict__ qkeyT,
                const unsigned short* __restrict__ mkt,
                const int* __restrict__ qlist, const int* __restrict__ qcnt,
                unsigned char* __restrict__ bcnt8, unsigned* __restrict__ bucket) {
  int lane = threadIdx.x & 63;
  int gid = (blockIdx.x << 2) + (threadIdx.x >> 6);   // global wave id, 0..6271
  int seg = gid & (NSEG_ - 1);
  int t   = gid >> 3;            // 0..783
  int mg  = t % MG32_;
  int b   = t / MG32_;
  int mc = qcnt[b];
  if (mg * 32 >= mc) return;
  int t0 = (NT32_ * seg) / NSEG_;
  int t1 = (NT32_ * (seg + 1)) / NSEG_;
  int l31 = lane & 31, lhi = lane >> 5;

  // Q fragments from fp32 qkeyT (x40 prefolded), converted in-reg once per wave
  int cm = mg * 32 + l31;
  int col = (cm < mc) ? qlist[b * M_ + cm] : qlist[b * M_];
  int mo  = (cm < mc) ? col : -1;
  const float* qrowf = qkeyT + ((size_t)b * M_ + col) * DK_ + lhi * 8;
  bf16x8 qf[8];
  #pragma unroll
  for (int kc = 0; kc < 8; ++kc) {
    float4 v0 = *(const float4*)&qrowf[kc * 16];
    float4 v1 = *(const float4*)&qrowf[kc * 16 + 4];
    bf16x8 q;
    q[0] = (short)f2bf(v0.x); q[1] = (short)f2bf(v0.y);
    q[2] = (short)f2bf(v0.z); q[3] = (short)f2bf(v0.w);
    q[4] = (short)f2bf(v1.x); q[5] = (short)f2bf(v1.y);
    q[6] = (short)f2bf(v1.z); q[7] = (short)f2bf(v1.w);
    qf[kc] = q;
  }

  const unsigned short* A_b = mkt + (size_t)b * (NT32_ * 4096) + lane * 8;
  float runmax = -3.0e38f;
  unsigned slot = 0;                      // private slot counter (register)
  size_t bbase = (size_t)(b * M_ + (mo >= 0 ? mo : 0)) * STRD_ + (seg * 2 + lhi) * CAP_;

  auto loadA = [&](bf16x8* dst, int tt) {
    const unsigned short* p = A_b + (size_t)tt * 4096;
    #pragma unroll
    for (int kc = 0; kc < 8; ++kc) dst[kc] = *(const bf16x8*)(p + kc * 512);
  };
  auto comp2 = [&](const bf16x8* Aa, const bf16x8* Ab, f32x16& xa, f32x16& xb) {
    #pragma unroll
    for (int r = 0; r < 16; ++r) { xa[r] = 0.f; xb[r] = 0.f; }
    #pragma unroll
    for (int kc = 0; kc < 8; ++kc) {     // two independent 8-deep chains, interleaved
      xa = __builtin_amdgcn_mfma_f32_32x32x16_bf16(Aa[kc], qf[kc], xa, 0, 0, 0);
      xb = __builtin_amdgcn_mfma_f32_32x32x16_bf16(Ab[kc], qf[kc], xb, 0, 0, 0);
    }
  };
  auto comp1 = [&](const bf16x8* Aa, f32x16& xa) {
    #pragma unroll
    for (int r = 0; r < 16; ++r) xa[r] = 0.f;
    #pragma unroll
    for (int kc = 0; kc < 8; ++kc)
      xa = __builtin_amdgcn_mfma_f32_32x32x16_bf16(Aa[kc], qf[kc], xa, 0, 0, 0);
  };
  auto epi = [&](const f32x16& acc, int tt) {
    float cmxl = acc[0];
    #pragma unroll
    for (int r = 1; r < 16; ++r) cmxl = fmaxf(cmxl, acc[r]);
    float cmx = fmaxf(cmxl, __shfl_xor(cmxl, 32));
    runmax = fmaxf(runmax, cmx);          // masked rows score exactly 0, never dominate
    if (mo >= 0 && cmxl >= runmax - MARGIN_) {   // skip-guard
      float thr = runmax - MARGIN_;
      #pragma unroll
      for (int r = 0; r < 16; ++r) {
        const int pos = (r & 3) + ((r >> 2) << 3);
        if (acc[r] >= thr) {              // fire-and-forget store, reg slot ctr
          if (slot < (unsigned)CAP_)
            bucket[bbase + slot] = (unsigned)(tt * 32 + pos + (lhi << 2));
          ++slot;
        }
      }
    }
  };

  bf16x8 A0[8], A1[8];
  int tt = t0;
  loadA(A0, tt);
  if (tt + 1 < t1) loadA(A1, tt + 1);
  while (tt + 1 < t1) {
    f32x16 xa, xb;
    comp2(A0, A1, xa, xb);
    int nx = tt + 2;
    if (nx < t1) {                     // prefetch next pair before epilogue VALU
      loadA(A0, nx);
      if (nx + 1 < t1) loadA(A1, nx + 1);
    }
    epi(xa, tt);
    epi(xb, tt + 1);
    tt = nx;
  }
  if (tt < t1) {                       // odd tail tile
    f32x16 xa;
    comp1(A0, xa);
    epi(xa, tt);
  }
  if (mo >= 0)                         // final count, plain byte store (unique owner)
    bcnt8[((size_t)(b * M_ + mo) << 4) + (seg * 2 + lhi)] =
        (unsigned char)(slot > 255u ? 255u : slot);
}

__device__ __forceinline__ float dot128(const float* __restrict__ q,
                                        const float* __restrict__ k) {
  float s = 0.f;
  #pragma unroll 8
  for (int i = 0; i < DK_; i += 4) {
    float4 a = *(const float4*)&q[i];
    float4 bb = *(const float4*)&k[i];
    s += a.x * bb.x + a.y * bb.y + a.z * bb.z + a.w * bb.w;
  }
  return s;
}

// ---- PV: one wave per active column; gather 16 mini-buckets (<=192, 3 chunks) ----
__global__ __launch_bounds__(256)
void pv_exact(const float* __restrict__ qkeyT, const float* __restrict__ mkeyT,
              const unsigned short* __restrict__ mvalT,
              const int* __restrict__ qlist, const int* __restrict__ qcnt,
              const int* __restrict__ mmask,
              const unsigned char* __restrict__ bcnt8, const unsigned* __restrict__ bucket,
              unsigned short* __restrict__ outT) {
  int b = blockIdx.y;
  int wv = threadIdx.x >> 6, lane = threadIdx.x & 63;
  int c = blockIdx.x * 4 + wv;
  if (c >= qcnt[b]) return;
  int m = qlist[b * M_ + c];
  const float* qrow = qkeyT + ((size_t)b * M_ + m) * DK_;
  float acc[8] = {0.f, 0.f, 0.f, 0.f, 0.f, 0.f, 0.f, 0.f};
  float lsum = 0.f;

  // 16 sub-counts for this column (u8 x16 = one 16B load)
  uint4 cw = *(const uint4*)(bcnt8 + ((size_t)(b * M_ + m) << 4));
  unsigned cn[16];
  #pragma unroll
  for (int i = 0; i < 16; ++i) {
    unsigned wrd = (i < 4) ? cw.x : (i < 8) ? cw.y : (i < 12) ? cw.z : cw.w;
    cn[i] = (wrd >> ((i & 3) * 8)) & 0xffu;
  }
  bool ovf = false;
  unsigned total = 0;
  #pragma unroll
  for (int i = 0; i < 16; ++i) { ovf |= (cn[i] > (unsigned)CAP_); total += cn[i]; }

  if (!ovf) {
    size_t colb = (size_t)(b * M_ + m) * STRD_;
    auto gather = [&](unsigned idx) -> int {
      int n = -1;
      unsigned off = idx;
      #pragma unroll
      for (int s = 0; s < 16; ++s) {
        unsigned cc = cn[s];
        if (n < 0) {
          if (off < cc) n = (int)bucket[colb + s * CAP_ + off];
          else off -= cc;
        }
      }
      return n;
    };
    int nn[3]; float ss[3];
    #pragma unroll
    for (int ch = 0; ch < 3; ++ch) { nn[ch] = -1; ss[ch] = -3.0e38f; }
    #pragma unroll
    for (int ch = 0; ch < 3; ++ch) {
      unsigned idx = ch * 64 + lane;
      if (idx < total) {
        int n = gather(idx);
        if (n >= 0 && mmask[b * N_ + n] == 0) n = -1;   // drop masked strays
        nn[ch] = n;
        if (n >= 0) ss[ch] = dot128(qrow, mkeyT + ((size_t)b * N_ + n) * DK_);
      }
    }
    float mx = fmaxf(fmaxf(ss[0], ss[1]), ss[2]);
    #pragma unroll
    for (int o = 32; o > 0; o >>= 1) mx = fmaxf(mx, __shfl_xor(mx, o));
    float ee[3];
    #pragma unroll
    for (int ch = 0; ch < 3; ++ch) {
      ee[ch] = (nn[ch] >= 0 && ss[ch] >= mx - TH_) ? expf(ss[ch] - mx) : 0.f;
      lsum += ee[ch];
    }
    #pragma unroll
    for (int o = 32; o > 0; o >>= 1) lsum += __shfl_xor(lsum, o);
    #pragma unroll
    for (int ch = 0; ch < 3; ++ch) {
      unsigned long long alive = __ballot(ee[ch] > 0.f);
      while (alive) {
        int lb = __ffsll((unsigned long long)alive) - 1;
        alive &= alive - 1;
        float w = __shfl(ee[ch], lb);
        int nnn = __shfl(nn[ch], lb);
        u16x8 vvv = *(const u16x8*)(mvalT + ((size_t)b * N_ + nnn) * DV_ + lane * 8);
        #pragma unroll
        for (int r = 0; r < 8; ++r) acc[r] += w * bf2f(vvv[r]);
      }
    }
  } else {
    // overflow fallback (rare): exact dense two-pass over all active n
    float mx = -3.0e38f;
    for (int base = 0; base < N_; base += 64) {
      int n = base + lane;
      float sv = -3.0e38f;
      if (mmask[b * N_ + n] != 0)
        sv = dot128(qrow, mkeyT + ((size_t)b * N_ + n) * DK_);
      mx = fmaxf(mx, sv);
    }
    #pragma unroll
    for (int o = 32; o > 0; o >>= 1) mx = fmaxf(mx, __shfl_xor(mx, o));
    for (int base = 0; base < N_; base += 64) {
      int n = base + lane;
      bool act = (mmask[b * N_ + n] != 0);
      float sv = -3.0e38f;
      if (act) sv = dot128(qrow, mkeyT + ((size_t)b * N_ + n) * DK_);
      float e = (act && sv >= mx - TH_) ? expf(sv - mx) : 0.f;
      lsum += e;
      unsigned long long alive = __ballot(e > 0.f);
      while (alive) {
        int lb = __ffsll((unsigned long long)alive) - 1;
        alive &= alive - 1;
        float w = __shfl(e, lb);
        int nnn = __shfl(n, lb);
        u16x8 vvv = *(const u16x8*)(mvalT + ((size_t)b * N_ + nnn) * DV_ + lane * 8);
        #pragma unroll
        for (int r = 0; r < 8; ++r) acc[r] += w * bf2f(vvv[r]);
      }
    }
    #pragma unroll
    for (int o = 32; o > 0; o >>= 1) lsum += __shfl_xor(lsum, o);
  }

  float inv = (lsum > 0.f) ? 1.0f / lsum : 0.0f;
  u16x8 ov;
  #pragma unroll
  for (int r = 0; r < 8; ++r) ov[r] = f2bf(acc[r] * inv);
  *(u16x8*)(outT + ((size_t)b * M_ + m) * DV_ + lane * 8) = ov;
}

// ---- transpose outT bf16 [B][M][Dv] -> out fp32 [B][Dv][M], applying qmask ----
__global__ __launch_bounds__(256)
void finalize_T(const unsigned short* __restrict__ outT, const int* __restrict__ qmask,
                float* __restrict__ out) {
  __shared__ float T[64][65];
  int b = blockIdx.z, dvt = blockIdx.y, mt = blockIdx.x;
  int lane = threadIdx.x & 63, ri = threadIdx.x >> 6;
  #pragma unroll
  for (int k = 0; k < 16; ++k) {
    int ml = ri * 16 + k;
    int m = mt * 64 + ml;
    bool act = (qmask[b * M_ + m] != 0);
    T[ml][lane] = act ? bf2f(outT[((size_t)b * M_ + m) * DV_ + dvt * 64 + lane]) : 0.f;
  }
  __syncthreads();
  #pragma unroll
  for (int k = 0; k < 16; ++k) {
    int dvl = ri * 16 + k;
    out[((size_t)b * DV_ + dvt * 64 + dvl) * M_ + mt * 64 + lane] = T[lane][dvl];
  }
}

extern "C" void kernel_launch(void* const* d_in, const int* in_sizes, int n_in,
                              void* d_out, int out_size, void* d_ws, size_t ws_size,
                              hipStream_t stream) {
  const float* qkey  = (const float*)d_in[0];
  const int*   qmask = (const int*)d_in[1];
  const float* mkey  = (const float*)d_in[2];
  const float* mval  = (const float*)d_in[3];
  const int*   mmask = (const int*)d_in[4];
  float* out = (float*)d_out;

  uint8_t* w = (uint8_t*)d_ws;
  unsigned char*  bcnt8  = (unsigned char*)(w + 0);         // B*M*16 u8 -> 401408
  int*            qcnt   = (int*)(w + 401408);
  int*            qlist  = (int*)(w + 401536);              // B*M -> 501888
  unsigned*       bucket = (unsigned*)(w + 501888);         // B*M*16*12 u32 -> 19769472
  float*          qkeyT  = (float*)(w + 19769472);          // B*M*128 f32 (x40)
  float*          mkeyT  = (float*)(w + 32614528);          // B*N*128 f32 (exact)
  unsigned short* mkt    = (unsigned short*)(w + 58304640); // B*196*8KB bf16 tiled
  unsigned short* outTb  = (unsigned short*)(w + 71149696); // B*M*512 bf16
  unsigned short* mvalT  = (unsigned short*)(w + 96839808); // B*N*512 bf16
  // end: 148,220,032 bytes == workspace size proven available in round 3

  prep_kernel<<<8632, 256, 0, stream>>>(qkey, qmask, mkey, mval, mmask,
                                        qkeyT, mkeyT, mkt, mvalT, qlist, qcnt);

  // 6272 static waves (8b x 98mg x 8seg) = 1568 blocks of 4 independent waves
  score_mfma<<<B_ * MG32_ * NSEG_ / 4, 256, 0, stream>>>(
      qkeyT, mkt, qlist, qcnt, bcnt8, bucket);

  pv_exact<<<dim3(M_ / 4, B_), 256, 0, stream>>>(
      qkeyT, mkeyT, mvalT, qlist, qcnt, mmask, bcnt8, bucket, outTb);

  finalize_T<<<dim3(M_ / 64, DV_ / 64, B_), 256, 0, stream>>>(outTb, qmask, out);
}

// Round 12
// 209.082 us; speedup vs baseline: 3.4832x; 2.5474x over previous
//
#include <hip/hip_runtime.h>
#include <stdint.h>

#define B_    8
#define DK_   128
#define DV_   512
#define M_    3136      // H*W
#define N_    6272      // T*H*W
#define NT32_ 196       // N_/32 tiles of 32 n
#define MG32_ 98        // M_/32 static m-groups of 32
#define NSEG_ 8
#define TH_   30.0f
#define MARGIN_ 36.0f
#define CAP_  24        // u16 slots per (column, segment, lane-half) owner stream
#define OCAP_ 64        // u16 overflow slots per column
#define STRD_ (16 * CAP_)   // u16 per column (primary)

typedef short bf16x8 __attribute__((ext_vector_type(8)));
typedef float f32x16 __attribute__((ext_vector_type(16)));
typedef unsigned short u16x8 __attribute__((ext_vector_type(8)));

__device__ __forceinline__ unsigned short f2bf(float x) {
  unsigned u = __float_as_uint(x);
  return (unsigned short)((u + 0x7fffu + ((u >> 16) & 1u)) >> 16);
}
__device__ __forceinline__ float bf2f(unsigned short h) {
  return __uint_as_float(((unsigned)h) << 16);
}

// ---- fused prep: vectorized transposes + q-scan + ocnt zero ----
// grid: [0,784) qkeyT; [784,2352) mkeyT + mkt(tiled, mask-zeroed);
//       [2352,8624) mvalT; [8624,8632) q scan; [8632,8657) zero ocnt
__global__ __launch_bounds__(256)
void prep_kernel(const float* __restrict__ qkey, const int* __restrict__ qmask,
                 const float* __restrict__ mkey, const float* __restrict__ mval,
                 const int* __restrict__ mmask,
                 float* __restrict__ qkeyT,
                 float* __restrict__ mkeyT, unsigned short* __restrict__ mkt,
                 unsigned short* __restrict__ mvalT,
                 int* __restrict__ qlist, int* __restrict__ qcnt,
                 unsigned* __restrict__ ocnt_z) {
  __shared__ float T[64][65];
  int r = blockIdx.x;
  int tid = threadIdx.x;
  int r16 = tid >> 4, c4 = (tid & 15) << 2;
  if (r < 784) {                       // qkey [B][128][M] -> fp32 [B][M][128], x40
    int xt = r % 49, dt = (r / 49) & 1, b = r / 98;
    const float* src = qkey + ((size_t)b * DK_ + dt * 64) * M_ + xt * 64;
    #pragma unroll
    for (int i = 0; i < 4; ++i) {
      int row = i * 16 + r16;
      float4 v = *(const float4*)&src[(size_t)row * M_ + c4];
      T[row][c4] = v.x; T[row][c4 + 1] = v.y; T[row][c4 + 2] = v.z; T[row][c4 + 3] = v.w;
    }
    __syncthreads();
    #pragma unroll
    for (int i = 0; i < 4; ++i) {
      int xl = i * 16 + r16;
      float4 v = make_float4(40.f * T[c4][xl], 40.f * T[c4 + 1][xl],
                             40.f * T[c4 + 2][xl], 40.f * T[c4 + 3][xl]);
      *(float4*)&qkeyT[((size_t)b * M_ + xt * 64 + xl) * DK_ + dt * 64 + c4] = v;
    }
  } else if (r < 2352) {               // mkey -> fp32 T (exact) + bf16 MFMA-tiled (mask-zeroed)
    int r2 = r - 784;
    int xt = r2 % 98, dt = (r2 / 98) & 1, b = r2 / 196;
    const float* src = mkey + ((size_t)b * DK_ + dt * 64) * N_ + xt * 64;
    #pragma unroll
    for (int i = 0; i < 4; ++i) {
      int row = i * 16 + r16;
      float4 v = *(const float4*)&src[(size_t)row * N_ + c4];
      T[row][c4] = v.x; T[row][c4 + 1] = v.y; T[row][c4 + 2] = v.z; T[row][c4 + 3] = v.w;
    }
    __syncthreads();
    #pragma unroll
    for (int i = 0; i < 4; ++i) {
      int xl = i * 16 + r16;
      int n = xt * 64 + xl;
      bool act = (mmask[b * N_ + n] != 0);
      float4 v = make_float4(T[c4][xl], T[c4 + 1][xl], T[c4 + 2][xl], T[c4 + 3][xl]);
      size_t idx = ((size_t)b * N_ + n) * DK_ + dt * 64 + c4;
      *(float4*)&mkeyT[idx] = v;
      ushort4 h;
      if (act) { h.x = f2bf(v.x); h.y = f2bf(v.y); h.z = f2bf(v.z); h.w = f2bf(v.w); }
      else     { h.x = 0; h.y = 0; h.z = 0; h.w = 0; }
      // tiled layout: [tile32][kc8][lane64][8bf16]; lane = ((k>>3)&1)*32 + (n&31)
      int k = dt * 64 + c4;
      int tile = n >> 5;
      int kc = k >> 4;
      int ln = (((k >> 3) & 1) << 5) | (n & 31);
      size_t ta = (size_t)b * (NT32_ * 4096) +
                  (((size_t)(tile * 8 + kc) * 64 + ln) << 3) + (k & 7);
      *(ushort4*)&mkt[ta] = h;
    }
  } else if (r < 8624) {               // mval -> bf16 [B][N][512]
    int r3 = r - 2352;
    int nt = r3 % 98, dvt = (r3 / 98) & 7, b = r3 / 784;
    const float* src = mval + ((size_t)b * DV_ + dvt * 64) * N_ + nt * 64;
    #pragma unroll
    for (int i = 0; i < 4; ++i) {
      int row = i * 16 + r16;
      float4 v = *(const float4*)&src[(size_t)row * N_ + c4];
      T[row][c4] = v.x; T[row][c4 + 1] = v.y; T[row][c4 + 2] = v.z; T[row][c4 + 3] = v.w;
    }
    __syncthreads();
    #pragma unroll
    for (int i = 0; i < 4; ++i) {
      int xl = i * 16 + r16;
      ushort4 h;
      h.x = f2bf(T[c4][xl]); h.y = f2bf(T[c4 + 1][xl]);
      h.z = f2bf(T[c4 + 2][xl]); h.w = f2bf(T[c4 + 3][xl]);
      *(ushort4*)&mvalT[((size_t)b * N_ + nt * 64 + xl) * DV_ + dvt * 64 + c4] = h;
    }
  } else if (r < 8632) {               // q-mask compaction
    int b = r - 8624;
    __shared__ int wsum[4];
    __shared__ int cbase;
    int lane = tid & 63, wv = tid >> 6;
    if (tid == 0) cbase = 0;
    __syncthreads();
    for (int base = 0; base < M_; base += 256) {
      int i = base + tid;
      int flag = (i < M_) ? (qmask[b * M_ + i] != 0) : 0;
      unsigned long long bal = __ballot(flag);
      int prefix = __popcll(bal & ((1ull << lane) - 1ull));
      if (lane == 0) wsum[wv] = __popcll(bal);
      __syncthreads();
      int woff = 0;
      for (int t = 0; t < wv; ++t) woff += wsum[t];
      int total = wsum[0] + wsum[1] + wsum[2] + wsum[3];
      if (flag) qlist[b * M_ + cbase + woff + prefix] = i;
      __syncthreads();
      if (tid == 0) cbase += total;
      __syncthreads();
    }
    if (tid == 0) qcnt[b] = cbase;
  } else {                             // zero ocnt (25 x 4096B padded region)
    unsigned* p = ocnt_z + (size_t)(r - 8632) * 1024;
    for (int i = tid; i < 1024; i += 256) p[i] = 0u;
  }
}

// ---- bf16-MFMA score: atomic-free primary buckets + rare atomic overflow ----
// one wave = one (batch, 32-m-group, n-segment); owner = (column, seg, lane-half)
__global__ __launch_bounds__(256)
void score_mfma(const float* __restrict__ qkeyT,
                const unsigned short* __restrict__ mkt,
                const int* __restrict__ qlist, const int* __restrict__ qcnt,
                unsigned char* __restrict__ bcnt8, unsigned short* __restrict__ bucket,
                unsigned* __restrict__ ocnt, unsigned short* __restrict__ obucket) {
  int lane = threadIdx.x & 63;
  int gid = (blockIdx.x << 2) + (threadIdx.x >> 6);   // global wave id, 0..6271
  int seg = gid & (NSEG_ - 1);
  int t   = gid >> 3;            // 0..783
  int mg  = t % MG32_;
  int b   = t / MG32_;
  int mc = qcnt[b];
  if (mg * 32 >= mc) return;
  int t0 = (NT32_ * seg) / NSEG_;
  int t1 = (NT32_ * (seg + 1)) / NSEG_;
  int l31 = lane & 31, lhi = lane >> 5;

  // Q fragments from fp32 qkeyT (x40 prefolded), converted in-reg once per wave
  int cm = mg * 32 + l31;
  int col = (cm < mc) ? qlist[b * M_ + cm] : qlist[b * M_];
  int mo  = (cm < mc) ? col : -1;
  const float* qrowf = qkeyT + ((size_t)b * M_ + col) * DK_ + lhi * 8;
  bf16x8 qf[8];
  #pragma unroll
  for (int kc = 0; kc < 8; ++kc) {
    float4 v0 = *(const float4*)&qrowf[kc * 16];
    float4 v1 = *(const float4*)&qrowf[kc * 16 + 4];
    bf16x8 q;
    q[0] = (short)f2bf(v0.x); q[1] = (short)f2bf(v0.y);
    q[2] = (short)f2bf(v0.z); q[3] = (short)f2bf(v0.w);
    q[4] = (short)f2bf(v1.x); q[5] = (short)f2bf(v1.y);
    q[6] = (short)f2bf(v1.z); q[7] = (short)f2bf(v1.w);
    qf[kc] = q;
  }

  const unsigned short* A_b = mkt + (size_t)b * (NT32_ * 4096) + lane * 8;
  float runmax = -3.0e38f;
  unsigned slot = 0;                      // private slot counter (register)
  int colid = b * M_ + (mo >= 0 ? mo : 0);
  size_t bbase = (size_t)colid * STRD_ + (seg * 2 + lhi) * CAP_;

  auto loadA = [&](bf16x8* dst, int tt) {
    const unsigned short* p = A_b + (size_t)tt * 4096;
    #pragma unroll
    for (int kc = 0; kc < 8; ++kc) dst[kc] = *(const bf16x8*)(p + kc * 512);
  };
  auto comp2 = [&](const bf16x8* Aa, const bf16x8* Ab, f32x16& xa, f32x16& xb) {
    #pragma unroll
    for (int r = 0; r < 16; ++r) { xa[r] = 0.f; xb[r] = 0.f; }
    #pragma unroll
    for (int kc = 0; kc < 8; ++kc) {     // two independent 8-deep chains, interleaved
      xa = __builtin_amdgcn_mfma_f32_32x32x16_bf16(Aa[kc], qf[kc], xa, 0, 0, 0);
      xb = __builtin_amdgcn_mfma_f32_32x32x16_bf16(Ab[kc], qf[kc], xb, 0, 0, 0);
    }
  };
  auto comp1 = [&](const bf16x8* Aa, f32x16& xa) {
    #pragma unroll
    for (int r = 0; r < 16; ++r) xa[r] = 0.f;
    #pragma unroll
    for (int kc = 0; kc < 8; ++kc)
      xa = __builtin_amdgcn_mfma_f32_32x32x16_bf16(Aa[kc], qf[kc], xa, 0, 0, 0);
  };
  auto epi = [&](const f32x16& acc, int tt) {
    float cmxl = acc[0];
    #pragma unroll
    for (int r = 1; r < 16; ++r) cmxl = fmaxf(cmxl, acc[r]);
    float cmx = fmaxf(cmxl, __shfl_xor(cmxl, 32));
    runmax = fmaxf(runmax, cmx);          // masked rows score exactly 0, never dominate
    if (mo >= 0 && cmxl >= runmax - MARGIN_) {   // skip-guard
      float thr = runmax - MARGIN_;
      #pragma unroll
      for (int r = 0; r < 16; ++r) {
        const int pos = (r & 3) + ((r >> 2) << 3);
        if (acc[r] >= thr) {
          unsigned short nv = (unsigned short)(tt * 32 + pos + (lhi << 2));
          if (slot < (unsigned)CAP_) {
            bucket[bbase + slot] = nv;     // fire-and-forget, reg slot ctr
          } else {                          // rare: per-column atomic overflow
            unsigned os = atomicAdd(&ocnt[colid], 1u);
            if (os < (unsigned)OCAP_) obucket[(size_t)colid * OCAP_ + os] = nv;
          }
          ++slot;
        }
      }
    }
  };

  bf16x8 A0[8], A1[8];
  int tt = t0;
  loadA(A0, tt);
  if (tt + 1 < t1) loadA(A1, tt + 1);
  while (tt + 1 < t1) {
    f32x16 xa, xb;
    comp2(A0, A1, xa, xb);
    int nx = tt + 2;
    if (nx < t1) {                     // prefetch next pair before epilogue VALU
      loadA(A0, nx);
      if (nx + 1 < t1) loadA(A1, nx + 1);
    }
    epi(xa, tt);
    epi(xb, tt + 1);
    tt = nx;
  }
  if (tt < t1) {                       // odd tail tile
    f32x16 xa;
    comp1(A0, xa);
    epi(xa, tt);
  }
  if (mo >= 0)                         // final count, plain byte store (unique owner)
    bcnt8[((size_t)(b * M_ + mo) << 4) + (seg * 2 + lhi)] =
        (unsigned char)(slot > 255u ? 255u : slot);
}

__device__ __forceinline__ float dot128(const float* __restrict__ q,
                                        const float* __restrict__ k) {
  float s = 0.f;
  #pragma unroll 8
  for (int i = 0; i < DK_; i += 4) {
    float4 a = *(const float4*)&q[i];
    float4 bb = *(const float4*)&k[i];
    s += a.x * bb.x + a.y * bb.y + a.z * bb.z + a.w * bb.w;
  }
  return s;
}

// ---- PV: one wave per active column; primary + overflow gather, exact rescore ----
__global__ __launch_bounds__(256)
void pv_exact(const float* __restrict__ qkeyT, const float* __restrict__ mkeyT,
              const unsigned short* __restrict__ mvalT,
              const int* __restrict__ qlist, const int* __restrict__ qcnt,
              const int* __restrict__ mmask,
              const unsigned char* __restrict__ bcnt8, const unsigned short* __restrict__ bucket,
              const unsigned* __restrict__ ocnt, const unsigned short* __restrict__ obucket,
              unsigned short* __restrict__ outT) {
  int b = blockIdx.y;
  int wv = threadIdx.x >> 6, lane = threadIdx.x & 63;
  int c = blockIdx.x * 4 + wv;
  if (c >= qcnt[b]) return;
  int m = qlist[b * M_ + c];
  int colid = b * M_ + m;
  const float* qrow = qkeyT + ((size_t)b * M_ + m) * DK_;
  float acc[8] = {0.f, 0.f, 0.f, 0.f, 0.f, 0.f, 0.f, 0.f};
  float lsum = 0.f;

  // 16 sub-counts (u8 x16 = one 16B load); primary holds first min(cnt,CAP) each
  uint4 cw = *(const uint4*)(bcnt8 + ((size_t)colid << 4));
  unsigned cn[16];
  #pragma unroll
  for (int i = 0; i < 16; ++i) {
    unsigned wrd = (i < 4) ? cw.x : (i < 8) ? cw.y : (i < 12) ? cw.z : cw.w;
    unsigned v = (wrd >> ((i & 3) * 8)) & 0xffu;
    cn[i] = (v > (unsigned)CAP_) ? (unsigned)CAP_ : v;
  }
  unsigned total_p = 0;
  #pragma unroll
  for (int i = 0; i < 16; ++i) total_p += cn[i];
  unsigned oc = ocnt[colid];
  bool ovf = (oc > (unsigned)OCAP_);
  unsigned total = total_p + (ovf ? 0u : oc);

  if (!ovf) {
    size_t colb = (size_t)colid * STRD_;
    size_t colo = (size_t)colid * OCAP_;
    auto gather = [&](unsigned idx) -> int {
      if (idx >= total_p) return (int)obucket[colo + (idx - total_p)];
      int n = -1;
      unsigned off = idx;
      #pragma unroll
      for (int s = 0; s < 16; ++s) {
        unsigned cc = cn[s];
        if (n < 0) {
          if (off < cc) n = (int)bucket[colb + s * CAP_ + off];
          else off -= cc;
        }
      }
      return n;
    };
    int nn[7]; float ss[7];
    #pragma unroll
    for (int ch = 0; ch < 7; ++ch) { nn[ch] = -1; ss[ch] = -3.0e38f; }
    #pragma unroll
    for (int ch = 0; ch < 7; ++ch) {
      unsigned idx = ch * 64 + lane;
      if (idx < total) {
        int n = gather(idx);
        if (n >= 0 && mmask[b * N_ + n] == 0) n = -1;   // drop masked strays
        nn[ch] = n;
        if (n >= 0) ss[ch] = dot128(qrow, mkeyT + ((size_t)b * N_ + n) * DK_);
      }
    }
    float mx = ss[0];
    #pragma unroll
    for (int ch = 1; ch < 7; ++ch) mx = fmaxf(mx, ss[ch]);
    #pragma unroll
    for (int o = 32; o > 0; o >>= 1) mx = fmaxf(mx, __shfl_xor(mx, o));
    float ee[7];
    #pragma unroll
    for (int ch = 0; ch < 7; ++ch) {
      ee[ch] = (nn[ch] >= 0 && ss[ch] >= mx - TH_) ? expf(ss[ch] - mx) : 0.f;
      lsum += ee[ch];
    }
    #pragma unroll
    for (int o = 32; o > 0; o >>= 1) lsum += __shfl_xor(lsum, o);
    #pragma unroll
    for (int ch = 0; ch < 7; ++ch) {
      unsigned long long alive = __ballot(ee[ch] > 0.f);
      while (alive) {
        int lb = __ffsll((unsigned long long)alive) - 1;
        alive &= alive - 1;
        float w = __shfl(ee[ch], lb);
        int nnn = __shfl(nn[ch], lb);
        u16x8 vvv = *(const u16x8*)(mvalT + ((size_t)b * N_ + nnn) * DV_ + lane * 8);
        #pragma unroll
        for (int r = 0; r < 8; ++r) acc[r] += w * bf2f(vvv[r]);
      }
    }
  } else {
    // last-resort fallback (statistically unreachable): exact dense two-pass
    float mx = -3.0e38f;
    for (int base = 0; base < N_; base += 64) {
      int n = base + lane;
      float sv = -3.0e38f;
      if (mmask[b * N_ + n] != 0)
        sv = dot128(qrow, mkeyT + ((size_t)b * N_ + n) * DK_);
      mx = fmaxf(mx, sv);
    }
    #pragma unroll
    for (int o = 32; o > 0; o >>= 1) mx = fmaxf(mx, __shfl_xor(mx, o));
    for (int base = 0; base < N_; base += 64) {
      int n = base + lane;
      bool act = (mmask[b * N_ + n] != 0);
      float sv = -3.0e38f;
      if (act) sv = dot128(qrow, mkeyT + ((size_t)b * N_ + n) * DK_);
      float e = (act && sv >= mx - TH_) ? expf(sv - mx) : 0.f;
      lsum += e;
      unsigned long long alive = __ballot(e > 0.f);
      while (alive) {
        int lb = __ffsll((unsigned long long)alive) - 1;
        alive &= alive - 1;
        float w = __shfl(e, lb);
        int nnn = __shfl(n, lb);
        u16x8 vvv = *(const u16x8*)(mvalT + ((size_t)b * N_ + nnn) * DV_ + lane * 8);
        #pragma unroll
        for (int r = 0; r < 8; ++r) acc[r] += w * bf2f(vvv[r]);
      }
    }
    #pragma unroll
    for (int o = 32; o > 0; o >>= 1) lsum += __shfl_xor(lsum, o);
  }

  float inv = (lsum > 0.f) ? 1.0f / lsum : 0.0f;
  u16x8 ov;
  #pragma unroll
  for (int r = 0; r < 8; ++r) ov[r] = f2bf(acc[r] * inv);
  *(u16x8*)(outT + ((size_t)colid) * DV_ + lane * 8) = ov;
}

// ---- transpose outT bf16 [B][M][Dv] -> out fp32 [B][Dv][M], applying qmask ----
__global__ __launch_bounds__(256)
void finalize_T(const unsigned short* __restrict__ outT, const int* __restrict__ qmask,
                float* __restrict__ out) {
  __shared__ float T[64][65];
  int b = blockIdx.z, dvt = blockIdx.y, mt = blockIdx.x;
  int lane = threadIdx.x & 63, ri = threadIdx.x >> 6;
  #pragma unroll
  for (int k = 0; k < 16; ++k) {
    int ml = ri * 16 + k;
    int m = mt * 64 + ml;
    bool act = (qmask[b * M_ + m] != 0);
    T[ml][lane] = act ? bf2f(outT[((size_t)b * M_ + m) * DV_ + dvt * 64 + lane]) : 0.f;
  }
  __syncthreads();
  #pragma unroll
  for (int k = 0; k < 16; ++k) {
    int dvl = ri * 16 + k;
    out[((size_t)b * DV_ + dvt * 64 + dvl) * M_ + mt * 64 + lane] = T[lane][dvl];
  }
}

extern "C" void kernel_launch(void* const* d_in, const int* in_sizes, int n_in,
                              void* d_out, int out_size, void* d_ws, size_t ws_size,
                              hipStream_t stream) {
  const float* qkey  = (const float*)d_in[0];
  const int*   qmask = (const int*)d_in[1];
  const float* mkey  = (const float*)d_in[2];
  const float* mval  = (const float*)d_in[3];
  const int*   mmask = (const int*)d_in[4];
  float* out = (float*)d_out;

  uint8_t* w = (uint8_t*)d_ws;
  unsigned char*  bcnt8   = (unsigned char*)(w + 0);          // B*M*16 u8 -> 401408
  unsigned*       ocnt    = (unsigned*)(w + 401408);          // B*M u32 pad -> 503808
  int*            qcnt    = (int*)(w + 503808);
  int*            qlist   = (int*)(w + 503936);               // B*M -> 604288
  unsigned short* bucket  = (unsigned short*)(w + 604288);    // B*M*16*24 u16 -> 19871872
  unsigned short* obucket = (unsigned short*)(w + 19871872);  // B*M*64 u16 -> 23083136
  float*          qkeyT   = (float*)(w + 23083136);           // B*M*128 f32 (x40)
  float*          mkeyT   = (float*)(w + 35928192);           // B*N*128 f32 (exact)
  unsigned short* mkt     = (unsigned short*)(w + 61618304);  // B*196*8KB bf16 tiled
  unsigned short* outTb   = (unsigned short*)(w + 74463360);  // B*M*512 bf16
  unsigned short* mvalT   = (unsigned short*)(w + 100153472); // B*N*512 bf16
  // end: 151,533,696 bytes (< 167,487,616 proven available by round 2's tier-A run)

  prep_kernel<<<8657, 256, 0, stream>>>(qkey, qmask, mkey, mval, mmask,
                                        qkeyT, mkeyT, mkt, mvalT, qlist, qcnt, ocnt);

  // 6272 static waves (8b x 98mg x 8seg) = 1568 blocks of 4 independent waves
  score_mfma<<<B_ * MG32_ * NSEG_ / 4, 256, 0, stream>>>(
      qkeyT, mkt, qlist, qcnt, bcnt8, bucket, ocnt, obucket);

  pv_exact<<<dim3(M_ / 4, B_), 256, 0, stream>>>(
      qkeyT, mkeyT, mvalT, qlist, qcnt, mmask, bcnt8, bucket, ocnt, obucket, outTb);

  finalize_T<<<dim3(M_ / 64, DV_ / 64, B_), 256, 0, stream>>>(outTb, qmask, out);
}